// Round 7
// baseline (3353.784 us; speedup 1.0000x reference)
//
// Round 13: GEMM wave-tile 128x64 (WTM=8) — cut LDS-read/MFMA 25%, 4 blocks/CU.
// R12 post-mortem: GEMM1 54.4us, MfmaUtil 25%, FETCH fixed (29MB), conflicts 0.
// New term identified: LDS-read BW — 64x64 wave-tile reads 0.5KB/MFMA = 2.1GB
// = ~30us/GEMM1 at 69TB/s, co-critical. Fix: 128x64 wave tile (8 frag rows):
// 12 reads/32 MFMA (-25%); 2-wave blocks @ ~205 regs -> 4 blocks/CU co-res
// (launch_bounds(128,2)), cheaper 2-wave barriers. WTM=4 instantiations
// (GEMM2/GEMM-dt) are algebra-identical to the proven R12 path.
#include <hip/hip_runtime.h>
#include <hip/hip_bf16.h>
#include <hip/hip_fp16.h>
#include <math.h>

#define B_ 8
#define S_ 2048
#define H_ 512
#define DI_ 1024
#define DS_ 16
#define DC_ 4
#define DR_ 32
#define NL_ 8
#define PF_ 4

typedef __hip_bfloat16 bf16;
typedef short bf16x8 __attribute__((ext_vector_type(8)));
typedef float f32x2 __attribute__((ext_vector_type(2)));
typedef float f32x4 __attribute__((ext_vector_type(4)));
typedef float f32x16 __attribute__((ext_vector_type(16)));
typedef unsigned short u16x8 __attribute__((ext_vector_type(8)));

static __device__ __forceinline__ float wred_sum(float v) {
#pragma unroll
  for (int o = 32; o; o >>= 1) v += __shfl_down(v, o, 64);
  return v;
}
static __device__ __forceinline__ float bf2f(unsigned short u) {
  return __uint_as_float(((unsigned)u) << 16);
}
static __device__ __forceinline__ float h2f(unsigned short u) {
  __half_raw r;
  r.x = u;
  return __half2float(r);
}
static __device__ __forceinline__ void st1(float* p, float v) { *p = v; }
static __device__ __forceinline__ void st1(bf16* p, float v) { *p = __float2bfloat16(v); }
static __device__ __forceinline__ void st1(__half* p, float v) { *p = __float2half(v); }
static __device__ __forceinline__ unsigned short f2bfu(float v) {
  bf16 b = __float2bfloat16(v);
  unsigned short u;
  __builtin_memcpy(&u, &b, 2);
  return u;
}

static __device__ __forceinline__ void gl_lds16(const unsigned short* g,
                                                unsigned short* l) {
  __builtin_amdgcn_global_load_lds(
      (const __attribute__((address_space(1))) void*)g,
      (__attribute__((address_space(3))) void*)l, 16, 0, 0);
}

// Wave-uniform 64B load through constant addrspace -> s_load_dwordx16 (SGPRs).
static __device__ __forceinline__ f32x16 ld_c16(const float* p) {
  return *(const __attribute__((address_space(4))) f32x16*)p;
}

// Scalar decay (scanB/k_scan). FAST: A[n] == -(n+1) => p[n] = q^(n+1).
template <bool FAST>
static __device__ __forceinline__ void decay16(float dt, const float* A,
                                               float* p) {
  if constexpr (FAST) {
    float q = __expf(-dt);
    float q2 = q * q, q3 = q2 * q, q4 = q2 * q2;
    p[0] = q; p[1] = q2; p[2] = q3; p[3] = q4;
    p[4] = q4 * q; p[5] = q4 * q2; p[6] = q4 * q3;
    float q8 = q4 * q4;
    p[7] = q8;
#pragma unroll
    for (int n = 0; n < 8; n++) p[8 + n] = q8 * p[n];
  } else {
#pragma unroll
    for (int n = 0; n < 16; n++) p[n] = __expf(dt * A[n]);
  }
}

// Packed decay: P[k] = (q^(2k+1), q^(2k+2)), log-depth via Q2/Q4/Q8 splats.
template <bool FAST>
static __device__ __forceinline__ void decay16p(float dt, const float* A,
                                                f32x2* P) {
  if constexpr (FAST) {
    float q = __expf(-dt);
    float q2 = q * q;
    f32x2 Q2 = {q2, q2};
    f32x2 Q4 = Q2 * Q2;
    f32x2 Q8 = Q4 * Q4;
    P[0][0] = q; P[0][1] = q2;
    P[1] = P[0] * Q2;
    P[2] = P[0] * Q4;
    P[3] = P[1] * Q4;
    P[4] = P[0] * Q8;
    P[5] = P[1] * Q8;
    P[6] = P[2] * Q8;
    P[7] = P[3] * Q8;
  } else {
#pragma unroll
    for (int k = 0; k < 8; k++) {
      P[k][0] = __expf(dt * A[2 * k]);
      P[k][1] = __expf(dt * A[2 * k + 1]);
    }
  }
}

// ---------------- MFMA GEMM: C[M,N] = X[M,K](bf16) @ W[N,K](bf16)^T ----------
// WTM = fragment rows per wave (4 -> 64x64 wave tile, 8 -> 128x64).
// ACT==1: softplus(v+bias). ACT==2: c<32 -> bf16 dtbf; else f32 C[c-32].
// ACT==3: c>=1024 -> silu(v). Grid blocks must be a multiple of 8 (XCD remap).
template <int BM, int BN, int BK, int WTM, int ACT, typename TC>
__global__ void __launch_bounds__((BM / (16 * WTM)) * (BN / 64) * 64,
                                  ((BM / (16 * WTM)) * (BN / 64)) == 2 ? 2 : 1)
k_mfma(const unsigned short* __restrict__ X, int lda,
       const unsigned short* __restrict__ W, int ldb,
       const float* __restrict__ bias, TC* __restrict__ C, long ldc, int K,
       unsigned short* __restrict__ dtbf) {
  constexpr int WN = BN / 64;
  constexpr int NW = (BM / (16 * WTM)) * WN;
  constexpr int RPS = 512 / BK;   // rows per 1024B staging segment
  constexpr int CH = BK / 8;      // 16B chunks per row
  constexpr int SMASK = (RPS - 1) & (CH - 1);
  constexpr int SEGS_A = BM / RPS;
  constexpr int SEGS = (BM + BN) / RPS;
  __shared__ unsigned short As[BM * BK];
  __shared__ unsigned short Bs[BN * BK];
  int tid = threadIdx.x;
  int wave = tid >> 6, lane = tid & 63;
  int wm = wave / WN, wn = wave % WN;
  // XCD-aware remap: each XCD owns contiguous row-panels x all columns.
  int nbx = gridDim.x;
  int nb = nbx * gridDim.y;
  int bid = blockIdx.y * nbx + blockIdx.x;
  int nid = (bid & 7) * (nb >> 3) + (bid >> 3);
  long row0 = (long)(nid / nbx) * BM;
  long col0 = (long)(nid % nbx) * BN;
  // staging lane decomposition
  int rs = lane / CH;             // row within segment
  int pch = lane % CH;            // 16B chunk position within row
  int kc = pch ^ (rs & (CH - 1)); // XOR-swizzled source k-chunk
  int fr = lane & 15;
  int q = lane >> 4;
  f32x4 acc[WTM][4] = {};
  for (int k0 = 0; k0 < K; k0 += BK) {
#pragma unroll
    for (int s = wave; s < SEGS; s += NW) {
      if (s < SEGS_A) {
        const unsigned short* g =
            X + (row0 + s * RPS + rs) * (long)lda + k0 + kc * 8;
        gl_lds16(g, &As[s * 512]);
      } else {
        int s2 = s - SEGS_A;
        const unsigned short* g =
            W + (col0 + s2 * RPS + rs) * (long)ldb + k0 + kc * 8;
        gl_lds16(g, &Bs[s2 * 512]);
      }
    }
    __syncthreads();
#pragma unroll
    for (int m = 0; m < BK / 32; m++) {
      int sl = (m * 4 + q) ^ (fr & SMASK);
      bf16x8 af[WTM], bfr[4];
#pragma unroll
      for (int i = 0; i < WTM; i++)
        af[i] = *(const bf16x8*)&As[(wm * WTM * 16 + i * 16 + fr) * BK + sl * 8];
#pragma unroll
      for (int j = 0; j < 4; j++)
        bfr[j] = *(const bf16x8*)&Bs[(wn * 64 + j * 16 + fr) * BK + sl * 8];
#pragma unroll
      for (int i = 0; i < WTM; i++)
#pragma unroll
        for (int j = 0; j < 4; j++)
          acc[i][j] = __builtin_amdgcn_mfma_f32_16x16x32_bf16(af[i], bfr[j],
                                                              acc[i][j], 0, 0, 0);
    }
    __syncthreads();
  }
#pragma unroll
  for (int i = 0; i < WTM; i++) {
#pragma unroll
    for (int j = 0; j < 4; j++) {
      long rbase = row0 + wm * WTM * 16 + i * 16 + ((lane >> 4) << 2);
      long c = col0 + wn * 64 + j * 16 + (lane & 15);
#pragma unroll
      for (int reg = 0; reg < 4; reg++) {
        float v = acc[i][j][reg];
        long r = rbase + reg;
        if constexpr (ACT == 2) {
          if (c < 32) st1((bf16*)&dtbf[r * 32 + c], v);
          else st1((float*)&C[r * ldc + (c - 32)], v);
        } else {
          if constexpr (ACT == 1) {
            v += bias[c];
            v = fmaxf(v, 0.f) + log1pf(__expf(-fabsf(v)));  // softplus
          }
          if constexpr (ACT == 3) {
            if (c >= 1024) v = v / (1.f + __expf(-v));  // silu(z)
          }
          st1(&C[r * ldc + c], v);
        }
      }
    }
  }
}

// ---------------- weight fp32 -> bf16 conversion ----------------
__global__ void k_convert4(const float* __restrict__ s0, int n0,
                           const float* __restrict__ s1, int n1,
                           const float* __restrict__ s2, int n2,
                           const float* __restrict__ s3, int n3,
                           bf16* __restrict__ d0, bf16* __restrict__ d1,
                           bf16* __restrict__ d2, bf16* __restrict__ d3) {
  int i = blockIdx.x * 256 + threadIdx.x;
  int t0 = n0 >> 2, t1 = t0 + (n1 >> 2), t2 = t1 + (n2 >> 2), t3 = t2 + (n3 >> 2);
  const float* s;
  bf16* d;
  int loc;
  if (i < t0) { s = s0; d = d0; loc = i; }
  else if (i < t1) { s = s1; d = d1; loc = i - t0; }
  else if (i < t2) { s = s2; d = d2; loc = i - t1; }
  else if (i < t3) { s = s3; d = d3; loc = i - t2; }
  else return;
  float4 v = ((const float4*)s)[loc];
  bf16* o = d + (long)loc * 4;
  st1(o + 0, v.x); st1(o + 1, v.y); st1(o + 2, v.z); st1(o + 3, v.w);
}

// ---------------- K1: embedding + LN + gate ----------------
__global__ void k_embed(const int* __restrict__ ids, const float* __restrict__ gate,
                        const float* __restrict__ wemb, const float* __restrict__ pos2,
                        const float* __restrict__ pe, const float* __restrict__ g,
                        const float* __restrict__ bta, bf16* __restrict__ seq) {
  int row = blockIdx.x;
  int s = row % S_;
  int t = threadIdx.x;
  int id = ids[row];
  float v[2];
#pragma unroll
  for (int i = 0; i < 2; i++) {
    int h = t + i * 256;
    v[i] = pos2[s * H_ + h] * wemb[(long)id * H_ + h] + pe[s * H_ + h];
  }
  float lsum = v[0] + v[1];
  float lsq = v[0] * v[0] + v[1] * v[1];
  __shared__ float smA[4], smB[4];
  int lane = t & 63, w = t >> 6;
  lsum = wred_sum(lsum);
  lsq = wred_sum(lsq);
  if (!lane) { smA[w] = lsum; smB[w] = lsq; }
  __syncthreads();
  float tot = smA[0] + smA[1] + smA[2] + smA[3];
  float totq = smB[0] + smB[1] + smB[2] + smB[3];
  float mu = tot * (1.f / H_);
  float var = totq * (1.f / H_) - mu * mu;
  float inv = rsqrtf(fmaxf(var, 0.f) + 1e-12f);
  float gt = gate[row];
#pragma unroll
  for (int i = 0; i < 2; i++) {
    int h = t + i * 256;
    st1(&seq[(long)row * H_ + h], gt * (g[h] * (v[i] - mu) * inv + bta[h]));
  }
}

// ---------------- conv (depthwise causal, DC=4) + silu, 8 elems/thread ------
__global__ void __launch_bounds__(256) k_conv(const bf16* __restrict__ xz,
                                              const float* __restrict__ cw,
                                              const float* __restrict__ cb,
                                              bf16* __restrict__ xc) {
  __shared__ float cwL[8 * 512];  // 8 rows x 128 float4
  __shared__ float cbL[8 * 128];
  int tid = threadIdx.x;
#pragma unroll
  for (int m = 0; m < 4; m++) {
    int dd = m * 256 + tid;  // one float4 == one d's 4 taps
    float4 v = ((const float4*)cw)[dd];
    int e = dd & 7, a = dd >> 3;
    *(float4*)&cwL[e * 512 + (((a + e) & 127) << 2)] = v;
  }
  {
    float4 v = ((const float4*)cb)[tid];
#pragma unroll
    for (int m = 0; m < 4; m++) {
      int dd = tid * 4 + m;
      int e = dd & 7, a = dd >> 3;
      cbL[e * 128 + ((a + e) & 127)] = ((const float*)&v)[m];
    }
  }
  __syncthreads();
  long idx = ((long)blockIdx.x * 256 + tid) * 8;
  int d0 = (int)(idx & 1023);
  int A = d0 >> 3;
  long bt = idx >> 10;
  int t = (int)(bt & 2047);  // wave-uniform
  const unsigned short* xbase = (const unsigned short*)xz + (bt - t) * 2048 + d0;
  f32x4 wk[8];
  float acc[8];
#pragma unroll
  for (int e = 0; e < 8; e++) {
    wk[e] = *(const f32x4*)&cwL[e * 512 + (((A + e) & 127) << 2)];
    acc[e] = cbL[e * 128 + ((A + e) & 127)];
  }
#pragma unroll
  for (int k = 0; k < 4; k++) {
    int ts = t + k - 3;
    if (ts >= 0) {
      u16x8 xv = *(const u16x8*)&xbase[(long)ts * 2048];
#pragma unroll
      for (int e = 0; e < 8; e++) acc[e] += wk[e][k] * bf2f(xv[e]);
    }
  }
  u16x8 ov;
#pragma unroll
  for (int e = 0; e < 8; e++) {
    float s = acc[e] / (1.f + __expf(-acc[e]));
    ov[e] = f2bfu(s);
  }
  *(u16x8*)((unsigned short*)xc + idx) = ov;
}

// ---------------- serial scan (fallback; z is pre-silu'd by GEMM1) ----------
__global__ void __launch_bounds__(64) k_scan(
    bf16* __restrict__ xzb, const bf16* __restrict__ xc,
    const float* __restrict__ xdb, const float* __restrict__ Alog,
    const float* __restrict__ Dp) {
  int idx = blockIdx.x * 64 + threadIdx.x;
  int half = idx & 1;
  int p = idx >> 1;
  int d = p & 1023;
  int b = p >> 10;
  int n0 = half * 8;
  float A[8];
#pragma unroll
  for (int n = 0; n < 8; n++) A[n] = -__expf(Alog[d * 16 + n0 + n]);
  float Dd = Dp[d];
  float h[8] = {0, 0, 0, 0, 0, 0, 0, 0};
  const __half* dtb = (const __half*)xzb + (long)b * S_ * 2048 + d;
  const unsigned short* xb = (const unsigned short*)xc + (long)b * S_ * DI_ + d;
  const unsigned short* zb = (const unsigned short*)xzb + (long)b * S_ * 2048 + DI_ + d;
  const float* bcb = xdb + (long)b * S_ * 32 + n0;
  bf16* yb = xzb + (long)b * S_ * 2048 + d;
  float dt_c = __half2float(dtb[0]);
  float x_c = bf2f(xb[0]);
  float z_c = bf2f(zb[0]);
  float Bc[8], Cc[8];
#pragma unroll
  for (int n = 0; n < 8; n++) { Bc[n] = bcb[n]; Cc[n] = bcb[16 + n]; }
  for (int t = 0; t < S_; t++) {
    float dt_n = 0.f, x_n = 0.f, z_n = 0.f, Bn[8], Cn[8];
#pragma unroll
    for (int n = 0; n < 8; n++) { Bn[n] = 0.f; Cn[n] = 0.f; }
    if (t + 1 < S_) {
      long o = (long)(t + 1);
      dt_n = __half2float(dtb[o * 2048]);
      x_n = bf2f(xb[o * DI_]);
      z_n = bf2f(zb[o * 2048]);
      const float* bc = bcb + o * 32;
#pragma unroll
      for (int n = 0; n < 8; n++) { Bn[n] = bc[n]; Cn[n] = bc[16 + n]; }
    }
    float dx = dt_c * x_c;
    float yacc = 0.f;
#pragma unroll
    for (int n = 0; n < 8; n++) {
      float hn = __expf(dt_c * A[n]) * h[n] + dx * Bc[n];
      h[n] = hn;
      yacc += hn * Cc[n];
    }
    yacc += __shfl_xor(yacc, 1, 64);
    if (!half) {
      st1(&yb[(long)t * 2048], (yacc + Dd * x_c) * z_c);  // z pre-silu'd
    }
    dt_c = dt_n; x_c = x_n; z_c = z_n;
#pragma unroll
    for (int n = 0; n < 8; n++) { Bc[n] = Bn[n]; Cc[n] = Cn[n]; }
  }
}

// ---------------- chunked scan phase A body (packed, 16 states/thread) ------
template <int LCv, bool FAST>
static __device__ __forceinline__ void scanA_body16(
    const __half* dtb, const unsigned short* xb, const float* bcb,
    const float* A, int t0, f32x2* h, float& sd) {
  float dtv[PF_], xv[PF_];
  f32x16 bv[2];
#pragma unroll
  for (int i = 0; i < PF_; i++) {
    long o = t0 + i;
    dtv[i] = __half2float(dtb[o * 2048]);
    xv[i] = bf2f(xb[o * DI_]);
  }
#pragma unroll
  for (int i = 0; i < 2; i++) bv[i] = ld_c16(bcb + (long)(t0 + i) * 32);
  // prefetch past chunk end is safe in phase A (read-only pass, c<=NC-2)
  for (int t = 0; t < LCv; t += PF_) {
#pragma unroll
    for (int u = 0; u < PF_; u++) {
      float dt_c = dtv[u], x_c = xv[u];
      f32x16 Bv = bv[u & 1];
      long ov = t0 + t + u + PF_;
      dtv[u] = __half2float(dtb[ov * 2048]);
      xv[u] = bf2f(xb[ov * DI_]);
      bv[u & 1] = ld_c16(bcb + (long)(t0 + t + u + 2) * 32);
      sd += dt_c;
      float dx = dt_c * x_c;
      f32x2 dx2 = {dx, dx};
      f32x2 P[8];
      decay16p<FAST>(dt_c, A, P);
      const f32x2* Bp = (const f32x2*)&Bv;
#pragma unroll
      for (int k = 0; k < 8; k++) h[k] = P[k] * h[k] + dx2 * Bp[k];
    }
  }
}

// grid (NCv-1)*32 x 256: chunks 0..NCv-2 (last chunk's h_final unused).
template <int NCv>
__global__ void __launch_bounds__(256) k_scanA(
    const bf16* __restrict__ xzb, const bf16* __restrict__ xc,
    const float* __restrict__ xdb, const float* __restrict__ Alog,
    __half* __restrict__ hf, __half* __restrict__ sdt) {
  constexpr int LCv = S_ / NCv;
  int bx = blockIdx.x;
  int c = bx >> 5;               // wave-uniform (from blockIdx only)
  int b = (bx >> 2) & 7;         // wave-uniform
  int d = ((bx & 3) << 8) + threadIdx.x;
  int p = (b << 10) + d;
  float A[16];
  bool fast = true;
#pragma unroll
  for (int n = 0; n < 16; n++) {
    A[n] = -__expf(Alog[d * 16 + n]);
    fast = fast && (fabsf(A[n] + (float)(n + 1)) < 1e-3f);
  }
  const __half* dtb = (const __half*)xzb + (long)b * S_ * 2048 + d;
  const unsigned short* xb = (const unsigned short*)xc + (long)b * S_ * DI_ + d;
  const float* bcb = xdb + (long)b * S_ * 32;  // uniform -> s_load
  int t0 = c * LCv;
  f32x2 h[8] = {};
  float sd = 0.f;
  if (fast) scanA_body16<LCv, true>(dtb, xb, bcb, A, t0, h, sd);
  else scanA_body16<LCv, false>(dtb, xb, bcb, A, t0, h, sd);
  __half* ho = hf + ((long)c * 8192 + p) * 16;
#pragma unroll
  for (int k = 0; k < 8; k++) {
    st1(&ho[2 * k], h[k][0]);
    st1(&ho[2 * k + 1], h[k][1]);
  }
  st1(&sdt[c * 8192 + p], sd);
}

// ---------------- scan phase B: fold chunk summaries -> prefix states -------
template <int NCv>
__global__ void __launch_bounds__(256) k_scanB(
    const float* __restrict__ Alog, __half* __restrict__ hf,
    const __half* __restrict__ sdt) {
  constexpr int M = NCv - 1;
  int i = blockIdx.x * 256 + threadIdx.x;  // 0..131071
  int n = i & 15;
  int p = i >> 4;
  int d = p & 1023;
  float An = -__expf(Alog[d * 16 + n]);
  float sdv[8], hjv[8];
#pragma unroll
  for (int k = 0; k < 8; k++) {
    int j = k < M ? k : M - 1;
    sdv[k] = h2f(((const unsigned short*)sdt)[j * 8192 + p]);
    hjv[k] = h2f(((const unsigned short*)hf)[((long)j * 8192 + p) * 16 + n]);
  }
  float H = 0.f;
  for (int j = 0; j < M; j++) {
    float sd = sdv[j & 7], hj = hjv[j & 7];
    int jn = j + 8;
    if (jn > M - 1) jn = M - 1;  // re-reads chunk-local value (unwritten yet)
    sdv[j & 7] = h2f(((const unsigned short*)sdt)[jn * 8192 + p]);
    hjv[j & 7] = h2f(((const unsigned short*)hf)[((long)jn * 8192 + p) * 16 + n]);
    H = __expf(sd * An) * H + hj;
    st1(&hf[((long)j * 8192 + p) * 16 + n], H);
  }
}

// ---------------- chunked scan phase C (packed, 16 states/thread) -----------
template <bool FAST>
static __device__ __forceinline__ void step16(float dt, float x, float zs,
                                              const f32x16& Bv, const f32x16& Cv,
                                              const float* A, float Dd,
                                              f32x2* h, bf16* yout) {
  f32x2 P[8];
  decay16p<FAST>(dt, A, P);
  float dx = dt * x;
  f32x2 dx2 = {dx, dx};
  const f32x2* Bp = (const f32x2*)&Bv;
  const f32x2* Cp = (const f32x2*)&Cv;
  f32x2 Y0 = {0.f, 0.f}, Y1 = {0.f, 0.f}, Y2 = {0.f, 0.f}, Y3 = {0.f, 0.f};
#pragma unroll
  for (int k = 0; k < 8; k += 4) {
    f32x2 h0 = P[k + 0] * h[k + 0] + dx2 * Bp[k + 0];
    f32x2 h1 = P[k + 1] * h[k + 1] + dx2 * Bp[k + 1];
    f32x2 h2 = P[k + 2] * h[k + 2] + dx2 * Bp[k + 2];
    f32x2 h3 = P[k + 3] * h[k + 3] + dx2 * Bp[k + 3];
    h[k + 0] = h0; h[k + 1] = h1; h[k + 2] = h2; h[k + 3] = h3;
    Y0 += h0 * Cp[k + 0];
    Y1 += h1 * Cp[k + 1];
    Y2 += h2 * Cp[k + 2];
    Y3 += h3 * Cp[k + 3];
  }
  f32x2 Yv = (Y0 + Y1) + (Y2 + Y3);
  float yacc = Yv[0] + Yv[1];
  st1(yout, (yacc + Dd * x) * zs);  // zs pre-silu'd by GEMM1
}

template <int LCv, bool FAST>
static __device__ __forceinline__ void scanC_body16(
    const __half* dtb, const unsigned short* xb, const unsigned short* zb,
    const float* bcb, bf16* yb, const float* A, int t0, float Dd, f32x2* h) {
  float dtv[PF_], xv[PF_], zv[PF_];
  f32x16 bv[2], cv[2];
#pragma unroll
  for (int i = 0; i < PF_; i++) {
    long o = t0 + i;
    dtv[i] = __half2float(dtb[o * 2048]);
    xv[i] = bf2f(xb[o * DI_]);
    zv[i] = bf2f(zb[o * 2048]);
  }
#pragma unroll
  for (int i = 0; i < 2; i++) {
    bv[i] = ld_c16(bcb + (long)(t0 + i) * 32);
    cv[i] = ld_c16(bcb + (long)(t0 + i) * 32 + 16);
  }
  // main loop: prefetch stays inside own chunk (y-store overwrites dt stream),
  // peeled epilogue instead of per-iteration clamp.
  for (int t = 0; t < LCv - PF_; t += PF_) {
#pragma unroll
    for (int u = 0; u < PF_; u++) {
      float dt_c = dtv[u], x_c = xv[u], z_c = zv[u];
      f32x16 Bv = bv[u & 1], Cv = cv[u & 1];
      long ov = t0 + t + u + PF_;  // <= t0+LCv-1, safe
      dtv[u] = __half2float(dtb[ov * 2048]);
      xv[u] = bf2f(xb[ov * DI_]);
      zv[u] = bf2f(zb[ov * 2048]);
      long os = t0 + t + u + 2;    // <= t0+LCv-3, safe
      bv[u & 1] = ld_c16(bcb + os * 32);
      cv[u & 1] = ld_c16(bcb + os * 32 + 16);
      step16<FAST>(dt_c, x_c, z_c, Bv, Cv, A, Dd, h,
                   yb + (long)(t0 + t + u) * 2048);
    }
  }
#pragma unroll
  for (int u = 0; u < PF_; u++) {  // t = LCv-4 .. LCv-1
    int tt = LCv - PF_ + u;
    f32x16 Bv, Cv;
    if (u < 2) {
      Bv = bv[u];
      Cv = cv[u];
    } else {
      Bv = ld_c16(bcb + (long)(t0 + tt) * 32);
      Cv = ld_c16(bcb + (long)(t0 + tt) * 32 + 16);
    }
    step16<FAST>(dtv[u], xv[u], zv[u], Bv, Cv, A, Dd, h,
                 yb + (long)(t0 + tt) * 2048);
  }
}

template <int NCv>
__global__ void __launch_bounds__(256) k_scanC(
    bf16* __restrict__ xzb, const bf16* __restrict__ xc,
    const float* __restrict__ xdb, const float* __restrict__ Alog,
    const float* __restrict__ Dp, const __half* __restrict__ hf,
    const __half* __restrict__ sdt) {
  constexpr int LCv = S_ / NCv;
  int bx = blockIdx.x;
  int c = bx >> 5;               // wave-uniform
  int b = (bx >> 2) & 7;         // wave-uniform
  int d = ((bx & 3) << 8) + threadIdx.x;
  int p = (b << 10) + d;
  float A[16];
  bool fast = true;
#pragma unroll
  for (int n = 0; n < 16; n++) {
    A[n] = -__expf(Alog[d * 16 + n]);
    fast = fast && (fabsf(A[n] + (float)(n + 1)) < 1e-3f);
  }
  float Dd = Dp[d];
  f32x2 h[8] = {};
  if (c > 0) {  // prefix state at end of chunk c-1, computed by k_scanB
    const unsigned short* hs =
        (const unsigned short*)hf + ((long)(c - 1) * 8192 + p) * 16;
    u16x8 a = *(const u16x8*)hs;
    u16x8 b2 = *(const u16x8*)(hs + 8);
#pragma unroll
    for (int k = 0; k < 4; k++) {
      h[k][0] = h2f(a[2 * k]);
      h[k][1] = h2f(a[2 * k + 1]);
      h[4 + k][0] = h2f(b2[2 * k]);
      h[4 + k][1] = h2f(b2[2 * k + 1]);
    }
  }
  const __half* dtb = (const __half*)xzb + (long)b * S_ * 2048 + d;
  const unsigned short* xb = (const unsigned short*)xc + (long)b * S_ * DI_ + d;
  const unsigned short* zb =
      (const unsigned short*)xzb + (long)b * S_ * 2048 + DI_ + d;
  const float* bcb = xdb + (long)b * S_ * 32;  // uniform -> s_load
  bf16* yb = xzb + (long)b * S_ * 2048 + d;
  int t0 = c * LCv;
  if (fast) scanC_body16<LCv, true>(dtb, xb, zb, bcb, yb, A, t0, Dd, h);
  else scanC_body16<LCv, false>(dtb, xb, zb, bcb, yb, A, t0, Dd, h);
}

// ---------------- residual + LN + gate (in-place on seq) ----------------
__global__ void k_resid_ln(const bf16* __restrict__ hb, const float* __restrict__ gate,
                           const float* __restrict__ g, const float* __restrict__ bta,
                           bf16* __restrict__ seq) {
  int row = blockIdx.x;
  int t = threadIdx.x;
  float v[2];
#pragma unroll
  for (int i = 0; i < 2; i++) {
    int h = t + i * 256;
    v[i] = bf2f(((const unsigned short*)hb)[(long)row * H_ + h]) +
           bf2f(((const unsigned short*)seq)[(long)row * H_ + h]);
  }
  float lsum = v[0] + v[1];
  float lsq = v[0] * v[0] + v[1] * v[1];
  __shared__ float smA[4], smB[4];
  int lane = t & 63, w = t >> 6;
  lsum = wred_sum(lsum);
  lsq = wred_sum(lsq);
  if (!lane) { smA[w] = lsum; smB[w] = lsq; }
  __syncthreads();
  float tot = smA[0] + smA[1] + smA[2] + smA[3];
  float totq = smB[0] + smB[1] + smB[2] + smB[3];
  float mu = tot * (1.f / H_);
  float var = totq * (1.f / H_) - mu * mu;
  float inv = rsqrtf(fmaxf(var, 0.f) + 1e-12f);
  float gt = gate[row];
#pragma unroll
  for (int i = 0; i < 2; i++) {
    int h = t + i * 256;
    st1(&seq[(long)row * H_ + h], gt * (g[h] * (v[i] - mu) * inv + bta[h]));
  }
}

// ---------------- max pool (two stage, vectorized) ----------------
__global__ void __launch_bounds__(64) k_pool1(const bf16* __restrict__ seq,
                                              const float* __restrict__ gate,
                                              float* __restrict__ part) {
  int blk = blockIdx.x;
  int b = blk >> 5, c = blk & 31;
  int h0 = threadIdx.x * 8;
  float m[8];
#pragma unroll
  for (int e = 0; e < 8; e++) m[e] = -3.4e38f;
  long r0 = (long)b * S_ + c * 64;
#pragma unroll 4
  for (int i = 0; i < 64; i++) {
    long r = r0 + i;
    u16x8 v = *(const u16x8*)&((const unsigned short*)seq)[r * H_ + h0];
    float g = gate[r];
#pragma unroll
    for (int e = 0; e < 8; e++) m[e] = fmaxf(m[e], bf2f(v[e]) * g);
  }
  float* o = part + ((long)b * 32 + c) * H_ + h0;
#pragma unroll
  for (int e = 0; e < 8; e++) o[e] = m[e];
}
__global__ void k_pool2(const float* __restrict__ part, float* __restrict__ pooled) {
  int idx = blockIdx.x * 256 + threadIdx.x;
  int b = idx >> 9, h = idx & 511;
  float m = -3.4e38f;
#pragma unroll
  for (int c = 0; c < 32; c++) m = fmaxf(m, part[((long)b * 32 + c) * H_ + h]);
  pooled[idx] = m;
}

// ---------------- dense2 + gelu_new ----------------
__global__ void k_feat(const float* __restrict__ pooled, const float* __restrict__ W2,
                       const float* __restrict__ b2, float* __restrict__ feat) {
  int b = blockIdx.x;
  int j = threadIdx.x;
  __shared__ float ps[512];
  ps[j] = pooled[b * 512 + j];
  __syncthreads();
  float acc = b2[j];
  const float4* wr = (const float4*)(W2 + (long)j * 512);
  const float4* p4 = (const float4*)ps;
  for (int k = 0; k < 128; k++) {
    float4 a = p4[k], bb = wr[k];
    acc += a.x * bb.x + a.y * bb.y + a.z * bb.z + a.w * bb.w;
  }
  float x = acc;
  float u = 0.7978845608028654f * (x + 0.044715f * x * x * x);
  feat[b * 512 + j] = 0.5f * x * (1.f + tanhf(u));
}

// ---------------- GroupNorm + FiLM(style) + head ----------------
__global__ void k_head(const float* __restrict__ feat, const float* __restrict__ age_sex,
                       const float* __restrict__ mw, const float* __restrict__ mb,
                       const float* __restrict__ gng, const float* __restrict__ gnb,
                       const float* __restrict__ hw, const float* __restrict__ hb,
                       float* __restrict__ out) {
  int b = blockIdx.x;
  int j = threadIdx.x;
  float f = feat[b * 512 + j];
  __shared__ float sA[8], sB[8];
  int lane = j & 63, w = j >> 6;
  float s1 = wred_sum(f);
  float s2 = wred_sum(f * f);
  if (!lane) { sA[w] = s1; sB[w] = s2; }
  __syncthreads();
  int g = j >> 7;
  float tot = sA[2 * g] + sA[2 * g + 1];
  float totq = sB[2 * g] + sB[2 * g + 1];
  float mu = tot * (1.f / 128.f);
  float var = totq * (1.f / 128.f) - mu * mu;
  float gn = (f - mu) * rsqrtf(fmaxf(var, 0.f) + 1e-5f) * gng[j] + gnb[j];
  float a0 = age_sex[b * 2], a1 = age_sex[b * 2 + 1];
  float sa = a0 * mw[j * 2] + a1 * mw[j * 2 + 1] + mb[j];
  sa = sa > 0.f ? sa : (__expf(sa) - 1.f);
  int j2 = 512 + j;
  float sb = a0 * mw[j2 * 2] + a1 * mw[j2 * 2 + 1] + mb[j2];
  sb = sb > 0.f ? sb : (__expf(sb) - 1.f);
  float feature = (1.f + sa) * gn + sb;
  out[16 + 16384 + b * 512 + j] = feature;
  float l0 = feature * hw[j];
  float l1 = feature * hw[512 + j];
  __syncthreads();
  l0 = wred_sum(l0);
  l1 = wred_sum(l1);
  if (!lane) { sA[w] = l0; sB[w] = l1; }
  __syncthreads();
  if (j == 0) {
    float t0 = 0.f, t1 = 0.f;
#pragma unroll
    for (int i = 0; i < 8; i++) { t0 += sA[i]; t1 += sB[i]; }
    out[b * 2 + 0] = t0 + hb[0];
    out[b * 2 + 1] = t1 + hb[1];
  }
}

__global__ void k_copy(const float* __restrict__ src, float* __restrict__ dst, int n) {
  int i = blockIdx.x * 256 + threadIdx.x;
  if (i < n) dst[i] = src[i];
}

// ---------------- launch ----------------
extern "C" void kernel_launch(void* const* d_in, const int* in_sizes, int n_in,
                              void* d_out, int out_size, void* d_ws, size_t ws_size,
                              hipStream_t stream) {
  const int* ids = (const int*)d_in[0];
  const float* gate = (const float*)d_in[1];
  const float* age_sex = (const float*)d_in[2];
  const float* word_emb = (const float*)d_in[3];
  const float* pos_emb2 = (const float*)d_in[4];
  const float* pe = (const float*)d_in[5];
  const float* emb_ln_g = (const float*)d_in[6];
  const float* emb_ln_b = (const float*)d_in[7];
  const float* in_proj_w = (const float*)d_in[8];
  const float* conv_w = (const float*)d_in[9];
  const float* conv_b = (const float*)d_in[10];
  const float* x_proj_w = (const float*)d_in[11];
  const float* dt_proj_w = (const float*)d_in[12];
  const float* dt_proj_b = (const float*)d_in[13];
  const float* A_log = (const float*)d_in[14];
  const float* D_param = (const float*)d_in[15];
  const float* out_proj_w = (const float*)d_in[16];
  const float* blk_ln_g = (const float*)d_in[17];
  const float* blk_ln_b = (const float*)d_in[18];
  const float* dense2_w = (const float*)d_in[19];
  const float* dense2_b = (const float*)d_in[20];
  const float* male_fc_w = (const float*)d_in[21];
  const float* male_fc_b = (const float*)d_in[22];
  const float* gn_g = (const float*)d_in[23];
  const float* gn_b = (const float*)d_in[24];
  const float* head_w = (const float*)d_in[25];
  const float* head_b = (const float*)d_in[26];
  float* out = (float*)d_out;

  // ws layout (bytes), fixed part = 120,586,240:
  //   seq 0 / xz 16,777,216 / xc 83,886,080 / xdb 117,440,512 (f32 [B,S,32])
  //   wo_b 119,537,664 / hf+aliases 120,586,240...
  char* w = (char*)d_ws;
  bf16* seq = (bf16*)(w);
  bf16* xz = (bf16*)(w + 16777216);
  bf16* xc = (bf16*)(w + 83886080);
  float* xdb = (float*)(w + 117440512);
  bf16* wo_b = (bf16*)(w + 119537664);
  bf16* wi_b = (bf16*)(w + 120586240);
  bf16* wx_b = (bf16*)(w + 122683392);
  bf16* wdt_b = (bf16*)(w + 122814464);
  bf16* xdt = (bf16*)(w + 122880000);
  __half* hf = (__half*)(w + 120586240);
  float* part = (float*)(w + 120586240);    // post-loop only, 512KB
  float* pooled = (float*)(w + 121110528);  // part + 524,288
  float* featp = (float*)(w + 121126912);   // pooled + 16,384

  const size_t base = 120586240;
  int NC = 0;
  if (ws_size >= base + (size_t)63 * 8192 * 34) NC = 64;
  else if (ws_size >= base + (size_t)31 * 8192 * 34) NC = 32;
  else if (ws_size >= base + (size_t)15 * 8192 * 34) NC = 16;
  __half* sdt = (__half*)(w + base + (size_t)(NC > 0 ? NC - 1 : 0) * 8192 * 32);

  k_embed<<<B_ * S_, 256, 0, stream>>>(ids, gate, word_emb, pos_emb2, pe, emb_ln_g,
                                       emb_ln_b, seq);

  const int nWi = 2 * DI_ * H_;
  const int nWx = 64 * DI_;
  const int nWdt = DI_ * DR_;
  const int nWo = H_ * DI_;
  const int cvt_blocks = (nWi + nWx + nWdt + nWo) / 4 / 256;

  for (int l = 0; l < NL_; l++) {
    const float* Wi = in_proj_w + (long)l * nWi;
    const float* cw = conv_w + (long)l * DI_ * DC_;
    const float* cb = conv_b + (long)l * DI_;
    const float* Wx = x_proj_w + (long)l * nWx;
    const float* Wdt = dt_proj_w + (long)l * nWdt;
    const float* bdt = dt_proj_b + (long)l * DI_;
    const float* Al = A_log + (long)l * DI_ * DS_;
    const float* Dl = D_param + (long)l * DI_;
    const float* Wo = out_proj_w + (long)l * nWo;
    const float* bg = blk_ln_g + (long)l * H_;
    const float* bb = blk_ln_b + (long)l * H_;

    k_convert4<<<cvt_blocks, 256, 0, stream>>>(Wi, nWi, Wx, nWx, Wdt, nWdt, Wo, nWo,
                                               wi_b, wx_b, wdt_b, wo_b);

    k_mfma<128, 128, 64, 8, 3, bf16><<<dim3(16, 128), 128, 0, stream>>>(
        (const unsigned short*)seq, H_, (const unsigned short*)wi_b, H_, nullptr,
        xz, 2048, H_, nullptr);
    k_conv<<<(B_ * S_ * DI_) / 8 / 256, 256, 0, stream>>>(xz, cw, cb, xc);
    k_mfma<64, 64, 64, 4, 2, float><<<dim3(1, 256), 64, 0, stream>>>(
        (const unsigned short*)xc, DI_, (const unsigned short*)wx_b, DI_, nullptr,
        xdb, 32, DI_, (unsigned short*)xdt);
    k_mfma<128, 128, 32, 4, 1, __half><<<dim3(8, 128), 256, 0, stream>>>(
        (const unsigned short*)xdt, 32, (const unsigned short*)wdt_b, DR_, bdt,
        (__half*)xz, 2048, DR_, nullptr);
    if (NC == 64) {
      k_scanA<64><<<63 * 32, 256, 0, stream>>>(xz, xc, xdb, Al, hf, sdt);
      k_scanB<64><<<512, 256, 0, stream>>>(Al, hf, sdt);
      k_scanC<64><<<64 * 32, 256, 0, stream>>>(xz, xc, xdb, Al, Dl, hf, sdt);
    } else if (NC == 32) {
      k_scanA<32><<<31 * 32, 256, 0, stream>>>(xz, xc, xdb, Al, hf, sdt);
      k_scanB<32><<<512, 256, 0, stream>>>(Al, hf, sdt);
      k_scanC<32><<<32 * 32, 256, 0, stream>>>(xz, xc, xdb, Al, Dl, hf, sdt);
    } else if (NC == 16) {
      k_scanA<16><<<15 * 32, 256, 0, stream>>>(xz, xc, xdb, Al, hf, sdt);
      k_scanB<16><<<512, 256, 0, stream>>>(Al, hf, sdt);
      k_scanC<16><<<16 * 32, 256, 0, stream>>>(xz, xc, xdb, Al, Dl, hf, sdt);
    } else {
      k_scan<<<256, 64, 0, stream>>>(xz, xc, xdb, Al, Dl);
    }
    k_mfma<128, 128, 64, 8, 0, bf16><<<dim3(4, 128), 128, 0, stream>>>(
        (const unsigned short*)xz, 2048, (const unsigned short*)wo_b, DI_, nullptr,
        xc, H_, DI_, nullptr);
    k_resid_ln<<<B_ * S_, 256, 0, stream>>>(xc, gate, bg, bb, seq);
  }

  k_pool1<<<B_ * 32, 64, 0, stream>>>(seq, gate, part);
  k_pool2<<<16, 256, 0, stream>>>(part, pooled);
  k_feat<<<B_, 512, 0, stream>>>(pooled, dense2_w, dense2_b, featp);
  k_head<<<B_, 512, 0, stream>>>(featp, age_sex, male_fc_w, male_fc_b, gn_g, gn_b,
                                 head_w, head_b, out);
  k_copy<<<(B_ * S_ + 255) / 256, 256, 0, stream>>>(gate, out + 16, B_ * S_);
}

// Round 8
// 2186.589 us; speedup vs baseline: 1.5338x; 1.5338x over previous
//
// Round 14: revert GEMM template to exact R12 (R13's WTM refactor regressed
// GEMM-dt 50->124us, unexplained; theory risk > reward) + cheapen softplus.
// R13 counters exposed: GEMM-dt was ~50us all along (hidden under GEMM1),
// VALUBusy 40%x124us = 50us = log1pf LIBCALL x 64 outputs/thread. Memory
// floor is ~5us. Fix: log1pf(expf(-|v|)) -> __logf(1+__expf(-|v|)) (hw
// v_log_f32/v_exp_f32, ~7 instr vs ~30; abs err ~6e-8, tol 0.03).
#include <hip/hip_runtime.h>
#include <hip/hip_bf16.h>
#include <hip/hip_fp16.h>
#include <math.h>

#define B_ 8
#define S_ 2048
#define H_ 512
#define DI_ 1024
#define DS_ 16
#define DC_ 4
#define DR_ 32
#define NL_ 8
#define PF_ 4

typedef __hip_bfloat16 bf16;
typedef short bf16x8 __attribute__((ext_vector_type(8)));
typedef float f32x2 __attribute__((ext_vector_type(2)));
typedef float f32x4 __attribute__((ext_vector_type(4)));
typedef float f32x16 __attribute__((ext_vector_type(16)));
typedef unsigned short u16x8 __attribute__((ext_vector_type(8)));

static __device__ __forceinline__ float wred_sum(float v) {
#pragma unroll
  for (int o = 32; o; o >>= 1) v += __shfl_down(v, o, 64);
  return v;
}
static __device__ __forceinline__ float bf2f(unsigned short u) {
  return __uint_as_float(((unsigned)u) << 16);
}
static __device__ __forceinline__ float h2f(unsigned short u) {
  __half_raw r;
  r.x = u;
  return __half2float(r);
}
static __device__ __forceinline__ void st1(float* p, float v) { *p = v; }
static __device__ __forceinline__ void st1(bf16* p, float v) { *p = __float2bfloat16(v); }
static __device__ __forceinline__ void st1(__half* p, float v) { *p = __float2half(v); }
static __device__ __forceinline__ unsigned short f2bfu(float v) {
  bf16 b = __float2bfloat16(v);
  unsigned short u;
  __builtin_memcpy(&u, &b, 2);
  return u;
}

static __device__ __forceinline__ void gl_lds16(const unsigned short* g,
                                                unsigned short* l) {
  __builtin_amdgcn_global_load_lds(
      (const __attribute__((address_space(1))) void*)g,
      (__attribute__((address_space(3))) void*)l, 16, 0, 0);
}

// Wave-uniform 64B load through constant addrspace -> s_load_dwordx16 (SGPRs).
static __device__ __forceinline__ f32x16 ld_c16(const float* p) {
  return *(const __attribute__((address_space(4))) f32x16*)p;
}

// Scalar decay (scanB/k_scan). FAST: A[n] == -(n+1) => p[n] = q^(n+1).
template <bool FAST>
static __device__ __forceinline__ void decay16(float dt, const float* A,
                                               float* p) {
  if constexpr (FAST) {
    float q = __expf(-dt);
    float q2 = q * q, q3 = q2 * q, q4 = q2 * q2;
    p[0] = q; p[1] = q2; p[2] = q3; p[3] = q4;
    p[4] = q4 * q; p[5] = q4 * q2; p[6] = q4 * q3;
    float q8 = q4 * q4;
    p[7] = q8;
#pragma unroll
    for (int n = 0; n < 8; n++) p[8 + n] = q8 * p[n];
  } else {
#pragma unroll
    for (int n = 0; n < 16; n++) p[n] = __expf(dt * A[n]);
  }
}

// Packed decay: P[k] = (q^(2k+1), q^(2k+2)), log-depth via Q2/Q4/Q8 splats.
template <bool FAST>
static __device__ __forceinline__ void decay16p(float dt, const float* A,
                                                f32x2* P) {
  if constexpr (FAST) {
    float q = __expf(-dt);
    float q2 = q * q;
    f32x2 Q2 = {q2, q2};
    f32x2 Q4 = Q2 * Q2;
    f32x2 Q8 = Q4 * Q4;
    P[0][0] = q; P[0][1] = q2;
    P[1] = P[0] * Q2;
    P[2] = P[0] * Q4;
    P[3] = P[1] * Q4;
    P[4] = P[0] * Q8;
    P[5] = P[1] * Q8;
    P[6] = P[2] * Q8;
    P[7] = P[3] * Q8;
  } else {
#pragma unroll
    for (int k = 0; k < 8; k++) {
      P[k][0] = __expf(dt * A[2 * k]);
      P[k][1] = __expf(dt * A[2 * k + 1]);
    }
  }
}

// ---------------- MFMA GEMM: C[M,N] = X[M,K](bf16) @ W[N,K](bf16)^T ----------
// ACT==1: softplus(v+bias). ACT==2: c<32 -> bf16 dtbf; else f32 C[c-32].
// ACT==3: c>=1024 -> silu(v). Grid blocks must be a multiple of 8 (XCD remap).
template <int BM, int BN, int BK, int ACT, typename TC>
__global__ void __launch_bounds__((BM / 64) * (BN / 64) * 64) k_mfma(
    const unsigned short* __restrict__ X, int lda,
    const unsigned short* __restrict__ W, int ldb,
    const float* __restrict__ bias, TC* __restrict__ C, long ldc, int K,
    unsigned short* __restrict__ dtbf) {
  constexpr int NW = (BM / 64) * (BN / 64);
  constexpr int WN = BN / 64;
  constexpr int RPS = 512 / BK;   // rows per 1024B staging segment
  constexpr int CH = BK / 8;      // 16B chunks per row
  constexpr int SEGS_A = BM / RPS;
  constexpr int SEGS = (BM + BN) / RPS;
  __shared__ unsigned short As[BM * BK];
  __shared__ unsigned short Bs[BN * BK];
  int tid = threadIdx.x;
  int wave = tid >> 6, lane = tid & 63;
  int wm = wave / WN, wn = wave % WN;
  // XCD-aware remap: each XCD owns contiguous row-panels x all columns.
  int nbx = gridDim.x;
  int nb = nbx * gridDim.y;
  int bid = blockIdx.y * nbx + blockIdx.x;
  int nid = (bid & 7) * (nb >> 3) + (bid >> 3);
  long row0 = (long)(nid / nbx) * BM;
  long col0 = (long)(nid % nbx) * BN;
  // staging lane decomposition
  int rs = lane / CH;             // row within segment
  int pch = lane % CH;            // 16B chunk position within row
  int kc = pch ^ (rs & (CH - 1)); // XOR-swizzled source k-chunk
  int fr = lane & 15;
  int q = lane >> 4;
  f32x4 acc[4][4] = {};
  for (int k0 = 0; k0 < K; k0 += BK) {
#pragma unroll
    for (int s = wave; s < SEGS; s += NW) {
      if (s < SEGS_A) {
        const unsigned short* g =
            X + (row0 + s * RPS + rs) * (long)lda + k0 + kc * 8;
        gl_lds16(g, &As[s * 512]);
      } else {
        int s2 = s - SEGS_A;
        const unsigned short* g =
            W + (col0 + s2 * RPS + rs) * (long)ldb + k0 + kc * 8;
        gl_lds16(g, &Bs[s2 * 512]);
      }
    }
    __syncthreads();
#pragma unroll
    for (int m = 0; m < BK / 32; m++) {
      int sl = (m * 4 + q) ^ (fr & (CH - 1));
      bf16x8 af[4], bfr[4];
#pragma unroll
      for (int i = 0; i < 4; i++)
        af[i] = *(const bf16x8*)&As[(wm * 64 + i * 16 + fr) * BK + sl * 8];
#pragma unroll
      for (int j = 0; j < 4; j++)
        bfr[j] = *(const bf16x8*)&Bs[(wn * 64 + j * 16 + fr) * BK + sl * 8];
#pragma unroll
      for (int i = 0; i < 4; i++)
#pragma unroll
        for (int j = 0; j < 4; j++)
          acc[i][j] = __builtin_amdgcn_mfma_f32_16x16x32_bf16(af[i], bfr[j],
                                                              acc[i][j], 0, 0, 0);
    }
    __syncthreads();
  }
#pragma unroll
  for (int i = 0; i < 4; i++) {
#pragma unroll
    for (int j = 0; j < 4; j++) {
      long rbase = row0 + wm * 64 + i * 16 + ((lane >> 4) << 2);
      long c = col0 + wn * 64 + j * 16 + (lane & 15);
#pragma unroll
      for (int reg = 0; reg < 4; reg++) {
        float v = acc[i][j][reg];
        long r = rbase + reg;
        if constexpr (ACT == 2) {
          if (c < 32) st1((bf16*)&dtbf[r * 32 + c], v);
          else st1((float*)&C[r * ldc + (c - 32)], v);
        } else {
          if constexpr (ACT == 1) {
            v += bias[c];
            // softplus via hw exp/log (was log1pf libcall: ~30 instr -> ~7)
            v = fmaxf(v, 0.f) + __logf(1.f + __expf(-fabsf(v)));
          }
          if constexpr (ACT == 3) {
            if (c >= 1024) v = v / (1.f + __expf(-v));  // silu(z)
          }
          st1(&C[r * ldc + c], v);
        }
      }
    }
  }
}

// ---------------- weight fp32 -> bf16 conversion ----------------
__global__ void k_convert4(const float* __restrict__ s0, int n0,
                           const float* __restrict__ s1, int n1,
                           const float* __restrict__ s2, int n2,
                           const float* __restrict__ s3, int n3,
                           bf16* __restrict__ d0, bf16* __restrict__ d1,
                           bf16* __restrict__ d2, bf16* __restrict__ d3) {
  int i = blockIdx.x * 256 + threadIdx.x;
  int t0 = n0 >> 2, t1 = t0 + (n1 >> 2), t2 = t1 + (n2 >> 2), t3 = t2 + (n3 >> 2);
  const float* s;
  bf16* d;
  int loc;
  if (i < t0) { s = s0; d = d0; loc = i; }
  else if (i < t1) { s = s1; d = d1; loc = i - t0; }
  else if (i < t2) { s = s2; d = d2; loc = i - t1; }
  else if (i < t3) { s = s3; d = d3; loc = i - t2; }
  else return;
  float4 v = ((const float4*)s)[loc];
  bf16* o = d + (long)loc * 4;
  st1(o + 0, v.x); st1(o + 1, v.y); st1(o + 2, v.z); st1(o + 3, v.w);
}

// ---------------- K1: embedding + LN + gate ----------------
__global__ void k_embed(const int* __restrict__ ids, const float* __restrict__ gate,
                        const float* __restrict__ wemb, const float* __restrict__ pos2,
                        const float* __restrict__ pe, const float* __restrict__ g,
                        const float* __restrict__ bta, bf16* __restrict__ seq) {
  int row = blockIdx.x;
  int s = row % S_;
  int t = threadIdx.x;
  int id = ids[row];
  float v[2];
#pragma unroll
  for (int i = 0; i < 2; i++) {
    int h = t + i * 256;
    v[i] = pos2[s * H_ + h] * wemb[(long)id * H_ + h] + pe[s * H_ + h];
  }
  float lsum = v[0] + v[1];
  float lsq = v[0] * v[0] + v[1] * v[1];
  __shared__ float smA[4], smB[4];
  int lane = t & 63, w = t >> 6;
  lsum = wred_sum(lsum);
  lsq = wred_sum(lsq);
  if (!lane) { smA[w] = lsum; smB[w] = lsq; }
  __syncthreads();
  float tot = smA[0] + smA[1] + smA[2] + smA[3];
  float totq = smB[0] + smB[1] + smB[2] + smB[3];
  float mu = tot * (1.f / H_);
  float var = totq * (1.f / H_) - mu * mu;
  float inv = rsqrtf(fmaxf(var, 0.f) + 1e-12f);
  float gt = gate[row];
#pragma unroll
  for (int i = 0; i < 2; i++) {
    int h = t + i * 256;
    st1(&seq[(long)row * H_ + h], gt * (g[h] * (v[i] - mu) * inv + bta[h]));
  }
}

// ---------------- conv (depthwise causal, DC=4) + silu, 8 elems/thread ------
__global__ void __launch_bounds__(256) k_conv(const bf16* __restrict__ xz,
                                              const float* __restrict__ cw,
                                              const float* __restrict__ cb,
                                              bf16* __restrict__ xc) {
  __shared__ float cwL[8 * 512];  // 8 rows x 128 float4
  __shared__ float cbL[8 * 128];
  int tid = threadIdx.x;
#pragma unroll
  for (int m = 0; m < 4; m++) {
    int dd = m * 256 + tid;  // one float4 == one d's 4 taps
    float4 v = ((const float4*)cw)[dd];
    int e = dd & 7, a = dd >> 3;
    *(float4*)&cwL[e * 512 + (((a + e) & 127) << 2)] = v;
  }
  {
    float4 v = ((const float4*)cb)[tid];
#pragma unroll
    for (int m = 0; m < 4; m++) {
      int dd = tid * 4 + m;
      int e = dd & 7, a = dd >> 3;
      cbL[e * 128 + ((a + e) & 127)] = ((const float*)&v)[m];
    }
  }
  __syncthreads();
  long idx = ((long)blockIdx.x * 256 + tid) * 8;
  int d0 = (int)(idx & 1023);
  int A = d0 >> 3;
  long bt = idx >> 10;
  int t = (int)(bt & 2047);  // wave-uniform
  const unsigned short* xbase = (const unsigned short*)xz + (bt - t) * 2048 + d0;
  f32x4 wk[8];
  float acc[8];
#pragma unroll
  for (int e = 0; e < 8; e++) {
    wk[e] = *(const f32x4*)&cwL[e * 512 + (((A + e) & 127) << 2)];
    acc[e] = cbL[e * 128 + ((A + e) & 127)];
  }
#pragma unroll
  for (int k = 0; k < 4; k++) {
    int ts = t + k - 3;
    if (ts >= 0) {
      u16x8 xv = *(const u16x8*)&xbase[(long)ts * 2048];
#pragma unroll
      for (int e = 0; e < 8; e++) acc[e] += wk[e][k] * bf2f(xv[e]);
    }
  }
  u16x8 ov;
#pragma unroll
  for (int e = 0; e < 8; e++) {
    float s = acc[e] / (1.f + __expf(-acc[e]));
    ov[e] = f2bfu(s);
  }
  *(u16x8*)((unsigned short*)xc + idx) = ov;
}

// ---------------- serial scan (fallback; z is pre-silu'd by GEMM1) ----------
__global__ void __launch_bounds__(64) k_scan(
    bf16* __restrict__ xzb, const bf16* __restrict__ xc,
    const float* __restrict__ xdb, const float* __restrict__ Alog,
    const float* __restrict__ Dp) {
  int idx = blockIdx.x * 64 + threadIdx.x;
  int half = idx & 1;
  int p = idx >> 1;
  int d = p & 1023;
  int b = p >> 10;
  int n0 = half * 8;
  float A[8];
#pragma unroll
  for (int n = 0; n < 8; n++) A[n] = -__expf(Alog[d * 16 + n0 + n]);
  float Dd = Dp[d];
  float h[8] = {0, 0, 0, 0, 0, 0, 0, 0};
  const __half* dtb = (const __half*)xzb + (long)b * S_ * 2048 + d;
  const unsigned short* xb = (const unsigned short*)xc + (long)b * S_ * DI_ + d;
  const unsigned short* zb = (const unsigned short*)xzb + (long)b * S_ * 2048 + DI_ + d;
  const float* bcb = xdb + (long)b * S_ * 32 + n0;
  bf16* yb = xzb + (long)b * S_ * 2048 + d;
  float dt_c = __half2float(dtb[0]);
  float x_c = bf2f(xb[0]);
  float z_c = bf2f(zb[0]);
  float Bc[8], Cc[8];
#pragma unroll
  for (int n = 0; n < 8; n++) { Bc[n] = bcb[n]; Cc[n] = bcb[16 + n]; }
  for (int t = 0; t < S_; t++) {
    float dt_n = 0.f, x_n = 0.f, z_n = 0.f, Bn[8], Cn[8];
#pragma unroll
    for (int n = 0; n < 8; n++) { Bn[n] = 0.f; Cn[n] = 0.f; }
    if (t + 1 < S_) {
      long o = (long)(t + 1);
      dt_n = __half2float(dtb[o * 2048]);
      x_n = bf2f(xb[o * DI_]);
      z_n = bf2f(zb[o * 2048]);
      const float* bc = bcb + o * 32;
#pragma unroll
      for (int n = 0; n < 8; n++) { Bn[n] = bc[n]; Cn[n] = bc[16 + n]; }
    }
    float dx = dt_c * x_c;
    float yacc = 0.f;
#pragma unroll
    for (int n = 0; n < 8; n++) {
      float hn = __expf(dt_c * A[n]) * h[n] + dx * Bc[n];
      h[n] = hn;
      yacc += hn * Cc[n];
    }
    yacc += __shfl_xor(yacc, 1, 64);
    if (!half) {
      st1(&yb[(long)t * 2048], (yacc + Dd * x_c) * z_c);  // z pre-silu'd
    }
    dt_c = dt_n; x_c = x_n; z_c = z_n;
#pragma unroll
    for (int n = 0; n < 8; n++) { Bc[n] = Bn[n]; Cc[n] = Cn[n]; }
  }
}

// ---------------- chunked scan phase A body (packed, 16 states/thread) ------
template <int LCv, bool FAST>
static __device__ __forceinline__ void scanA_body16(
    const __half* dtb, const unsigned short* xb, const float* bcb,
    const float* A, int t0, f32x2* h, float& sd) {
  float dtv[PF_], xv[PF_];
  f32x16 bv[2];
#pragma unroll
  for (int i = 0; i < PF_; i++) {
    long o = t0 + i;
    dtv[i] = __half2float(dtb[o * 2048]);
    xv[i] = bf2f(xb[o * DI_]);
  }
#pragma unroll
  for (int i = 0; i < 2; i++) bv[i] = ld_c16(bcb + (long)(t0 + i) * 32);
  // prefetch past chunk end is safe in phase A (read-only pass, c<=NC-2)
  for (int t = 0; t < LCv; t += PF_) {
#pragma unroll
    for (int u = 0; u < PF_; u++) {
      float dt_c = dtv[u], x_c = xv[u];
      f32x16 Bv = bv[u & 1];
      long ov = t0 + t + u + PF_;
      dtv[u] = __half2float(dtb[ov * 2048]);
      xv[u] = bf2f(xb[ov * DI_]);
      bv[u & 1] = ld_c16(bcb + (long)(t0 + t + u + 2) * 32);
      sd += dt_c;
      float dx = dt_c * x_c;
      f32x2 dx2 = {dx, dx};
      f32x2 P[8];
      decay16p<FAST>(dt_c, A, P);
      const f32x2* Bp = (const f32x2*)&Bv;
#pragma unroll
      for (int k = 0; k < 8; k++) h[k] = P[k] * h[k] + dx2 * Bp[k];
    }
  }
}

// grid (NCv-1)*32 x 256: chunks 0..NCv-2 (last chunk's h_final unused).
template <int NCv>
__global__ void __launch_bounds__(256) k_scanA(
    const bf16* __restrict__ xzb, const bf16* __restrict__ xc,
    const float* __restrict__ xdb, const float* __restrict__ Alog,
    __half* __restrict__ hf, __half* __restrict__ sdt) {
  constexpr int LCv = S_ / NCv;
  int bx = blockIdx.x;
  int c = bx >> 5;               // wave-uniform (from blockIdx only)
  int b = (bx >> 2) & 7;         // wave-uniform
  int d = ((bx & 3) << 8) + threadIdx.x;
  int p = (b << 10) + d;
  float A[16];
  bool fast = true;
#pragma unroll
  for (int n = 0; n < 16; n++) {
    A[n] = -__expf(Alog[d * 16 + n]);
    fast = fast && (fabsf(A[n] + (float)(n + 1)) < 1e-3f);
  }
  const __half* dtb = (const __half*)xzb + (long)b * S_ * 2048 + d;
  const unsigned short* xb = (const unsigned short*)xc + (long)b * S_ * DI_ + d;
  const float* bcb = xdb + (long)b * S_ * 32;  // uniform -> s_load
  int t0 = c * LCv;
  f32x2 h[8] = {};
  float sd = 0.f;
  if (fast) scanA_body16<LCv, true>(dtb, xb, bcb, A, t0, h, sd);
  else scanA_body16<LCv, false>(dtb, xb, bcb, A, t0, h, sd);
  __half* ho = hf + ((long)c * 8192 + p) * 16;
#pragma unroll
  for (int k = 0; k < 8; k++) {
    st1(&ho[2 * k], h[k][0]);
    st1(&ho[2 * k + 1], h[k][1]);
  }
  st1(&sdt[c * 8192 + p], sd);
}

// ---------------- scan phase B: fold chunk summaries -> prefix states -------
template <int NCv>
__global__ void __launch_bounds__(256) k_scanB(
    const float* __restrict__ Alog, __half* __restrict__ hf,
    const __half* __restrict__ sdt) {
  constexpr int M = NCv - 1;
  int i = blockIdx.x * 256 + threadIdx.x;  // 0..131071
  int n = i & 15;
  int p = i >> 4;
  int d = p & 1023;
  float An = -__expf(Alog[d * 16 + n]);
  float sdv[8], hjv[8];
#pragma unroll
  for (int k = 0; k < 8; k++) {
    int j = k < M ? k : M - 1;
    sdv[k] = h2f(((const unsigned short*)sdt)[j * 8192 + p]);
    hjv[k] = h2f(((const unsigned short*)hf)[((long)j * 8192 + p) * 16 + n]);
  }
  float H = 0.f;
  for (int j = 0; j < M; j++) {
    float sd = sdv[j & 7], hj = hjv[j & 7];
    int jn = j + 8;
    if (jn > M - 1) jn = M - 1;  // re-reads chunk-local value (unwritten yet)
    sdv[j & 7] = h2f(((const unsigned short*)sdt)[jn * 8192 + p]);
    hjv[j & 7] = h2f(((const unsigned short*)hf)[((long)jn * 8192 + p) * 16 + n]);
    H = __expf(sd * An) * H + hj;
    st1(&hf[((long)j * 8192 + p) * 16 + n], H);
  }
}

// ---------------- chunked scan phase C (packed, 16 states/thread) -----------
template <bool FAST>
static __device__ __forceinline__ void step16(float dt, float x, float zs,
                                              const f32x16& Bv, const f32x16& Cv,
                                              const float* A, float Dd,
                                              f32x2* h, bf16* yout) {
  f32x2 P[8];
  decay16p<FAST>(dt, A, P);
  float dx = dt * x;
  f32x2 dx2 = {dx, dx};
  const f32x2* Bp = (const f32x2*)&Bv;
  const f32x2* Cp = (const f32x2*)&Cv;
  f32x2 Y0 = {0.f, 0.f}, Y1 = {0.f, 0.f}, Y2 = {0.f, 0.f}, Y3 = {0.f, 0.f};
#pragma unroll
  for (int k = 0; k < 8; k += 4) {
    f32x2 h0 = P[k + 0] * h[k + 0] + dx2 * Bp[k + 0];
    f32x2 h1 = P[k + 1] * h[k + 1] + dx2 * Bp[k + 1];
    f32x2 h2 = P[k + 2] * h[k + 2] + dx2 * Bp[k + 2];
    f32x2 h3 = P[k + 3] * h[k + 3] + dx2 * Bp[k + 3];
    h[k + 0] = h0; h[k + 1] = h1; h[k + 2] = h2; h[k + 3] = h3;
    Y0 += h0 * Cp[k + 0];
    Y1 += h1 * Cp[k + 1];
    Y2 += h2 * Cp[k + 2];
    Y3 += h3 * Cp[k + 3];
  }
  f32x2 Yv = (Y0 + Y1) + (Y2 + Y3);
  float yacc = Yv[0] + Yv[1];
  st1(yout, (yacc + Dd * x) * zs);  // zs pre-silu'd by GEMM1
}

template <int LCv, bool FAST>
static __device__ __forceinline__ void scanC_body16(
    const __half* dtb, const unsigned short* xb, const unsigned short* zb,
    const float* bcb, bf16* yb, const float* A, int t0, float Dd, f32x2* h) {
  float dtv[PF_], xv[PF_], zv[PF_];
  f32x16 bv[2], cv[2];
#pragma unroll
  for (int i = 0; i < PF_; i++) {
    long o = t0 + i;
    dtv[i] = __half2float(dtb[o * 2048]);
    xv[i] = bf2f(xb[o * DI_]);
    zv[i] = bf2f(zb[o * 2048]);
  }
#pragma unroll
  for (int i = 0; i < 2; i++) {
    bv[i] = ld_c16(bcb + (long)(t0 + i) * 32);
    cv[i] = ld_c16(bcb + (long)(t0 + i) * 32 + 16);
  }
  // main loop: prefetch stays inside own chunk (y-store overwrites dt stream),
  // peeled epilogue instead of per-iteration clamp.
  for (int t = 0; t < LCv - PF_; t += PF_) {
#pragma unroll
    for (int u = 0; u < PF_; u++) {
      float dt_c = dtv[u], x_c = xv[u], z_c = zv[u];
      f32x16 Bv = bv[u & 1], Cv = cv[u & 1];
      long ov = t0 + t + u + PF_;  // <= t0+LCv-1, safe
      dtv[u] = __half2float(dtb[ov * 2048]);
      xv[u] = bf2f(xb[ov * DI_]);
      zv[u] = bf2f(zb[ov * 2048]);
      long os = t0 + t + u + 2;    // <= t0+LCv-3, safe
      bv[u & 1] = ld_c16(bcb + os * 32);
      cv[u & 1] = ld_c16(bcb + os * 32 + 16);
      step16<FAST>(dt_c, x_c, z_c, Bv, Cv, A, Dd, h,
                   yb + (long)(t0 + t + u) * 2048);
    }
  }
#pragma unroll
  for (int u = 0; u < PF_; u++) {  // t = LCv-4 .. LCv-1
    int tt = LCv - PF_ + u;
    f32x16 Bv, Cv;
    if (u < 2) {
      Bv = bv[u];
      Cv = cv[u];
    } else {
      Bv = ld_c16(bcb + (long)(t0 + tt) * 32);
      Cv = ld_c16(bcb + (long)(t0 + tt) * 32 + 16);
    }
    step16<FAST>(dtv[u], xv[u], zv[u], Bv, Cv, A, Dd, h,
                 yb + (long)(t0 + tt) * 2048);
  }
}

template <int NCv>
__global__ void __launch_bounds__(256) k_scanC(
    bf16* __restrict__ xzb, const bf16* __restrict__ xc,
    const float* __restrict__ xdb, const float* __restrict__ Alog,
    const float* __restrict__ Dp, const __half* __restrict__ hf,
    const __half* __restrict__ sdt) {
  constexpr int LCv = S_ / NCv;
  int bx = blockIdx.x;
  int c = bx >> 5;               // wave-uniform
  int b = (bx >> 2) & 7;         // wave-uniform
  int d = ((bx & 3) << 8) + threadIdx.x;
  int p = (b << 10) + d;
  float A[16];
  bool fast = true;
#pragma unroll
  for (int n = 0; n < 16; n++) {
    A[n] = -__expf(Alog[d * 16 + n]);
    fast = fast && (fabsf(A[n] + (float)(n + 1)) < 1e-3f);
  }
  float Dd = Dp[d];
  f32x2 h[8] = {};
  if (c > 0) {  // prefix state at end of chunk c-1, computed by k_scanB
    const unsigned short* hs =
        (const unsigned short*)hf + ((long)(c - 1) * 8192 + p) * 16;
    u16x8 a = *(const u16x8*)hs;
    u16x8 b2 = *(const u16x8*)(hs + 8);
#pragma unroll
    for (int k = 0; k < 4; k++) {
      h[k][0] = h2f(a[2 * k]);
      h[k][1] = h2f(a[2 * k + 1]);
      h[4 + k][0] = h2f(b2[2 * k]);
      h[4 + k][1] = h2f(b2[2 * k + 1]);
    }
  }
  const __half* dtb = (const __half*)xzb + (long)b * S_ * 2048 + d;
  const unsigned short* xb = (const unsigned short*)xc + (long)b * S_ * DI_ + d;
  const unsigned short* zb =
      (const unsigned short*)xzb + (long)b * S_ * 2048 + DI_ + d;
  const float* bcb = xdb + (long)b * S_ * 32;  // uniform -> s_load
  bf16* yb = xzb + (long)b * S_ * 2048 + d;
  int t0 = c * LCv;
  if (fast) scanC_body16<LCv, true>(dtb, xb, zb, bcb, yb, A, t0, Dd, h);
  else scanC_body16<LCv, false>(dtb, xb, zb, bcb, yb, A, t0, Dd, h);
}

// ---------------- residual + LN + gate (in-place on seq) ----------------
__global__ void k_resid_ln(const bf16* __restrict__ hb, const float* __restrict__ gate,
                           const float* __restrict__ g, const float* __restrict__ bta,
                           bf16* __restrict__ seq) {
  int row = blockIdx.x;
  int t = threadIdx.x;
  float v[2];
#pragma unroll
  for (int i = 0; i < 2; i++) {
    int h = t + i * 256;
    v[i] = bf2f(((const unsigned short*)hb)[(long)row * H_ + h]) +
           bf2f(((const unsigned short*)seq)[(long)row * H_ + h]);
  }
  float lsum = v[0] + v[1];
  float lsq = v[0] * v[0] + v[1] * v[1];
  __shared__ float smA[4], smB[4];
  int lane = t & 63, w = t >> 6;
  lsum = wred_sum(lsum);
  lsq = wred_sum(lsq);
  if (!lane) { smA[w] = lsum; smB[w] = lsq; }
  __syncthreads();
  float tot = smA[0] + smA[1] + smA[2] + smA[3];
  float totq = smB[0] + smB[1] + smB[2] + smB[3];
  float mu = tot * (1.f / H_);
  float var = totq * (1.f / H_) - mu * mu;
  float inv = rsqrtf(fmaxf(var, 0.f) + 1e-12f);
  float gt = gate[row];
#pragma unroll
  for (int i = 0; i < 2; i++) {
    int h = t + i * 256;
    st1(&seq[(long)row * H_ + h], gt * (g[h] * (v[i] - mu) * inv + bta[h]));
  }
}

// ---------------- max pool (two stage, vectorized) ----------------
__global__ void __launch_bounds__(64) k_pool1(const bf16* __restrict__ seq,
                                              const float* __restrict__ gate,
                                              float* __restrict__ part) {
  int blk = blockIdx.x;
  int b = blk >> 5, c = blk & 31;
  int h0 = threadIdx.x * 8;
  float m[8];
#pragma unroll
  for (int e = 0; e < 8; e++) m[e] = -3.4e38f;
  long r0 = (long)b * S_ + c * 64;
#pragma unroll 4
  for (int i = 0; i < 64; i++) {
    long r = r0 + i;
    u16x8 v = *(const u16x8*)&((const unsigned short*)seq)[r * H_ + h0];
    float g = gate[r];
#pragma unroll
    for (int e = 0; e < 8; e++) m[e] = fmaxf(m[e], bf2f(v[e]) * g);
  }
  float* o = part + ((long)b * 32 + c) * H_ + h0;
#pragma unroll
  for (int e = 0; e < 8; e++) o[e] = m[e];
}
__global__ void k_pool2(const float* __restrict__ part, float* __restrict__ pooled) {
  int idx = blockIdx.x * 256 + threadIdx.x;
  int b = idx >> 9, h = idx & 511;
  float m = -3.4e38f;
#pragma unroll
  for (int c = 0; c < 32; c++) m = fmaxf(m, part[((long)b * 32 + c) * H_ + h]);
  pooled[idx] = m;
}

// ---------------- dense2 + gelu_new ----------------
__global__ void k_feat(const float* __restrict__ pooled, const float* __restrict__ W2,
                       const float* __restrict__ b2, float* __restrict__ feat) {
  int b = blockIdx.x;
  int j = threadIdx.x;
  __shared__ float ps[512];
  ps[j] = pooled[b * 512 + j];
  __syncthreads();
  float acc = b2[j];
  const float4* wr = (const float4*)(W2 + (long)j * 512);
  const float4* p4 = (const float4*)ps;
  for (int k = 0; k < 128; k++) {
    float4 a = p4[k], bb = wr[k];
    acc += a.x * bb.x + a.y * bb.y + a.z * bb.z + a.w * bb.w;
  }
  float x = acc;
  float u = 0.7978845608028654f * (x + 0.044715f * x * x * x);
  feat[b * 512 + j] = 0.5f * x * (1.f + tanhf(u));
}

// ---------------- GroupNorm + FiLM(style) + head ----------------
__global__ void k_head(const float* __restrict__ feat, const float* __restrict__ age_sex,
                       const float* __restrict__ mw, const float* __restrict__ mb,
                       const float* __restrict__ gng, const float* __restrict__ gnb,
                       const float* __restrict__ hw, const float* __restrict__ hb,
                       float* __restrict__ out) {
  int b = blockIdx.x;
  int j = threadIdx.x;
  float f = feat[b * 512 + j];
  __shared__ float sA[8], sB[8];
  int lane = j & 63, w = j >> 6;
  float s1 = wred_sum(f);
  float s2 = wred_sum(f * f);
  if (!lane) { sA[w] = s1; sB[w] = s2; }
  __syncthreads();
  int g = j >> 7;
  float tot = sA[2 * g] + sA[2 * g + 1];
  float totq = sB[2 * g] + sB[2 * g + 1];
  float mu = tot * (1.f / 128.f);
  float var = totq * (1.f / 128.f) - mu * mu;
  float gn = (f - mu) * rsqrtf(fmaxf(var, 0.f) + 1e-5f) * gng[j] + gnb[j];
  float a0 = age_sex[b * 2], a1 = age_sex[b * 2 + 1];
  float sa = a0 * mw[j * 2] + a1 * mw[j * 2 + 1] + mb[j];
  sa = sa > 0.f ? sa : (__expf(sa) - 1.f);
  int j2 = 512 + j;
  float sb = a0 * mw[j2 * 2] + a1 * mw[j2 * 2 + 1] + mb[j2];
  sb = sb > 0.f ? sb : (__expf(sb) - 1.f);
  float feature = (1.f + sa) * gn + sb;
  out[16 + 16384 + b * 512 + j] = feature;
  float l0 = feature * hw[j];
  float l1 = feature * hw[512 + j];
  __syncthreads();
  l0 = wred_sum(l0);
  l1 = wred_sum(l1);
  if (!lane) { sA[w] = l0; sB[w] = l1; }
  __syncthreads();
  if (j == 0) {
    float t0 = 0.f, t1 = 0.f;
#pragma unroll
    for (int i = 0; i < 8; i++) { t0 += sA[i]; t1 += sB[i]; }
    out[b * 2 + 0] = t0 + hb[0];
    out[b * 2 + 1] = t1 + hb[1];
  }
}

__global__ void k_copy(const float* __restrict__ src, float* __restrict__ dst, int n) {
  int i = blockIdx.x * 256 + threadIdx.x;
  if (i < n) dst[i] = src[i];
}

// ---------------- launch ----------------
extern "C" void kernel_launch(void* const* d_in, const int* in_sizes, int n_in,
                              void* d_out, int out_size, void* d_ws, size_t ws_size,
                              hipStream_t stream) {
  const int* ids = (const int*)d_in[0];
  const float* gate = (const float*)d_in[1];
  const float* age_sex = (const float*)d_in[2];
  const float* word_emb = (const float*)d_in[3];
  const float* pos_emb2 = (const float*)d_in[4];
  const float* pe = (const float*)d_in[5];
  const float* emb_ln_g = (const float*)d_in[6];
  const float* emb_ln_b = (const float*)d_in[7];
  const float* in_proj_w = (const float*)d_in[8];
  const float* conv_w = (const float*)d_in[9];
  const float* conv_b = (const float*)d_in[10];
  const float* x_proj_w = (const float*)d_in[11];
  const float* dt_proj_w = (const float*)d_in[12];
  const float* dt_proj_b = (const float*)d_in[13];
  const float* A_log = (const float*)d_in[14];
  const float* D_param = (const float*)d_in[15];
  const float* out_proj_w = (const float*)d_in[16];
  const float* blk_ln_g = (const float*)d_in[17];
  const float* blk_ln_b = (const float*)d_in[18];
  const float* dense2_w = (const float*)d_in[19];
  const float* dense2_b = (const float*)d_in[20];
  const float* male_fc_w = (const float*)d_in[21];
  const float* male_fc_b = (const float*)d_in[22];
  const float* gn_g = (const float*)d_in[23];
  const float* gn_b = (const float*)d_in[24];
  const float* head_w = (const float*)d_in[25];
  const float* head_b = (const float*)d_in[26];
  float* out = (float*)d_out;

  // ws layout (bytes), fixed part = 120,586,240:
  //   seq 0 / xz 16,777,216 / xc 83,886,080 / xdb 117,440,512 (f32 [B,S,32])
  //   wo_b 119,537,664 / hf+aliases 120,586,240...
  char* w = (char*)d_ws;
  bf16* seq = (bf16*)(w);
  bf16* xz = (bf16*)(w + 16777216);
  bf16* xc = (bf16*)(w + 83886080);
  float* xdb = (float*)(w + 117440512);
  bf16* wo_b = (bf16*)(w + 119537664);
  bf16* wi_b = (bf16*)(w + 120586240);
  bf16* wx_b = (bf16*)(w + 122683392);
  bf16* wdt_b = (bf16*)(w + 122814464);
  bf16* xdt = (bf16*)(w + 122880000);
  __half* hf = (__half*)(w + 120586240);
  float* part = (float*)(w + 120586240);    // post-loop only, 512KB
  float* pooled = (float*)(w + 121110528);  // part + 524,288
  float* featp = (float*)(w + 121126912);   // pooled + 16,384

  const size_t base = 120586240;
  int NC = 0;
  if (ws_size >= base + (size_t)63 * 8192 * 34) NC = 64;
  else if (ws_size >= base + (size_t)31 * 8192 * 34) NC = 32;
  else if (ws_size >= base + (size_t)15 * 8192 * 34) NC = 16;
  __half* sdt = (__half*)(w + base + (size_t)(NC > 0 ? NC - 1 : 0) * 8192 * 32);

  k_embed<<<B_ * S_, 256, 0, stream>>>(ids, gate, word_emb, pos_emb2, pe, emb_ln_g,
                                       emb_ln_b, seq);

  const int nWi = 2 * DI_ * H_;
  const int nWx = 64 * DI_;
  const int nWdt = DI_ * DR_;
  const int nWo = H_ * DI_;
  const int cvt_blocks = (nWi + nWx + nWdt + nWo) / 4 / 256;

  for (int l = 0; l < NL_; l++) {
    const float* Wi = in_proj_w + (long)l * nWi;
    const float* cw = conv_w + (long)l * DI_ * DC_;
    const float* cb = conv_b + (long)l * DI_;
    const float* Wx = x_proj_w + (long)l * nWx;
    const float* Wdt = dt_proj_w + (long)l * nWdt;
    const float* bdt = dt_proj_b + (long)l * DI_;
    const float* Al = A_log + (long)l * DI_ * DS_;
    const float* Dl = D_param + (long)l * DI_;
    const float* Wo = out_proj_w + (long)l * nWo;
    const float* bg = blk_ln_g + (long)l * H_;
    const float* bb = blk_ln_b + (long)l * H_;

    k_convert4<<<cvt_blocks, 256, 0, stream>>>(Wi, nWi, Wx, nWx, Wdt, nWdt, Wo, nWo,
                                               wi_b, wx_b, wdt_b, wo_b);

    k_mfma<128, 128, 64, 3, bf16><<<dim3(16, 128), 256, 0, stream>>>(
        (const unsigned short*)seq, H_, (const unsigned short*)wi_b, H_, nullptr,
        xz, 2048, H_, nullptr);
    k_conv<<<(B_ * S_ * DI_) / 8 / 256, 256, 0, stream>>>(xz, cw, cb, xc);
    k_mfma<64, 64, 64, 2, float><<<dim3(1, 256), 64, 0, stream>>>(
        (const unsigned short*)xc, DI_, (const unsigned short*)wx_b, DI_, nullptr,
        xdb, 32, DI_, (unsigned short*)xdt);
    k_mfma<128, 128, 32, 1, __half><<<dim3(8, 128), 256, 0, stream>>>(
        (const unsigned short*)xdt, 32, (const unsigned short*)wdt_b, DR_, bdt,
        (__half*)xz, 2048, DR_, nullptr);
    if (NC == 64) {
      k_scanA<64><<<63 * 32, 256, 0, stream>>>(xz, xc, xdb, Al, hf, sdt);
      k_scanB<64><<<512, 256, 0, stream>>>(Al, hf, sdt);
      k_scanC<64><<<64 * 32, 256, 0, stream>>>(xz, xc, xdb, Al, Dl, hf, sdt);
    } else if (NC == 32) {
      k_scanA<32><<<31 * 32, 256, 0, stream>>>(xz, xc, xdb, Al, hf, sdt);
      k_scanB<32><<<512, 256, 0, stream>>>(Al, hf, sdt);
      k_scanC<32><<<32 * 32, 256, 0, stream>>>(xz, xc, xdb, Al, Dl, hf, sdt);
    } else if (NC == 16) {
      k_scanA<16><<<15 * 32, 256, 0, stream>>>(xz, xc, xdb, Al, hf, sdt);
      k_scanB<16><<<512, 256, 0, stream>>>(Al, hf, sdt);
      k_scanC<16><<<16 * 32, 256, 0, stream>>>(xz, xc, xdb, Al, Dl, hf, sdt);
    } else {
      k_scan<<<256, 64, 0, stream>>>(xz, xc, xdb, Al, Dl);
    }
    k_mfma<128, 128, 64, 0, bf16><<<dim3(4, 128), 256, 0, stream>>>(
        (const unsigned short*)xz, 2048, (const unsigned short*)wo_b, DI_, nullptr,
        xc, H_, DI_, nullptr);
    k_resid_ln<<<B_ * S_, 256, 0, stream>>>(xc, gate, bg, bb, seq);
  }

  k_pool1<<<B_ * 32, 64, 0, stream>>>(seq, gate, part);
  k_pool2<<<16, 256, 0, stream>>>(part, pooled);
  k_feat<<<B_, 512, 0, stream>>>(pooled, dense2_w, dense2_b, featp);
  k_head<<<B_, 512, 0, stream>>>(featp, age_sex, male_fc_w, male_fc_b, gn_g, gn_b,
                                 head_w, head_b, out);
  k_copy<<<(B_ * S_ + 255) / 256, 256, 0, stream>>>(gate, out + 16, B_ * S_);
}